// Round 8
// baseline (207.923 us; speedup 1.0000x reference)
//
#include <hip/hip_runtime.h>
#include <math.h>

#define T_TOK 8192
#define A_DIM 1024
#define E_DIM 512
#define S_SPAN 32768
#define HID 150

typedef __attribute__((ext_vector_type(8))) short short8;
typedef __attribute__((ext_vector_type(4))) float f32x4;

__device__ __forceinline__ unsigned short f2bf(float f) {
    unsigned int u = __builtin_bit_cast(unsigned int, f);
    u += 0x7FFFu + ((u >> 16) & 1u);          // RNE
    return (unsigned short)(u >> 16);
}
__device__ __forceinline__ float bf2f(unsigned int h16) {
    unsigned int u = h16 << 16;
    return __builtin_bit_cast(float, u);
}
__device__ __forceinline__ short8 cast8(f32x4 a, f32x4 b) {
    short8 r;
    r[0] = (short)f2bf(a.x); r[1] = (short)f2bf(a.y);
    r[2] = (short)f2bf(a.z); r[3] = (short)f2bf(a.w);
    r[4] = (short)f2bf(b.x); r[5] = (short)f2bf(b.y);
    r[6] = (short)f2bf(b.z); r[7] = (short)f2bf(b.w);
    return r;
}

// ---------------------------------------------------------------------------
// prep: 6 weight transposes into chunk-blocked layout Wb[c][n][k&31]
// (c = k>>5, n = output col 0..159) + width projection. 71 blocks.
// ---------------------------------------------------------------------------
struct WConv { const float* src; unsigned short* dst; int K0; int Kpad; int nblk; };
struct PrepTab {
    WConv g[6];
    const float* wt; const float* Ws1w; float* PW;
};

__global__ __launch_bounds__(256) void prep_kernel(PrepTab tab) {
    __shared__ unsigned short tile[64 * 161];
    int b = blockIdx.x;
    #pragma unroll
    for (int gi = 0; gi < 6; ++gi) {
        if (b < tab.g[gi].nblk) {
            const int k0 = b * 64;
            const int K0 = tab.g[gi].K0;
            const float* src = tab.g[gi].src;
            unsigned short* dst = tab.g[gi].dst;
            // read: [64 k-rows x 160 j-cols], coalesced on j
            for (int idx = threadIdx.x; idx < 64 * 160; idx += 256) {
                int kr = idx / 160, j = idx - kr * 160;
                int k = k0 + kr;
                float v = (j < HID && k < K0) ? src[(size_t)k * HID + j] : 0.f;
                tile[kr * 161 + j] = f2bf(v);
            }
            __syncthreads();
            // write blocked: dst[(k>>5)*5120 + j*32 + (k&31)]
            for (int idx = threadIdx.x; idx < 160 * 64; idx += 256) {
                int j = idx >> 6, kc = idx & 63;
                int k = k0 + kc;
                dst[(size_t)(k >> 5) * 5120 + j * 32 + (k & 31)] = tile[kc * 161 + j];
            }
            return;
        }
        b -= tab.g[gi].nblk;
    }
    int j = threadIdx.x;
    if (j < HID) {
        float acc = 0.f;
        for (int k = 0; k < 20; ++k)
            acc = fmaf(tab.wt[b * 20 + k], tab.Ws1w[k * HID + j], acc);
        tab.PW[b * HID + j] = acc;
    }
}

// ---------------------------------------------------------------------------
// barrier-free MFMA GEMM: per group C[M x 160] = A[M x K] @ W(bf16 blocked)
// block = 4 waves over 64 rows x 160 cols; wave (g = wid>>1, h = wid&1)
// covers rows g*32..+31 (2 m-frags) x cols h*80..+79 (5 n-tiles).
// W frags loaded global->VGPR (L1/L2-resident, chunk-blocked = dense 1KB/nt);
// 1-deep register prefetch; fp32 A cast in-reg AFTER the MFMA block.
// No __syncthreads in the K-loop.
// ---------------------------------------------------------------------------
struct GG {
    const void* A; int lda; int a_fp32;
    const unsigned short* W; int K; int nrb;
    unsigned short* outh; int ldo;
    const float* bias; int relu;
    const float* dotv; const float* dotb; float* dotout;
};
struct GTab { GG g[4]; int ng; };

__global__ __launch_bounds__(256, 2) void gemm_fused(GTab tab) {
    __shared__ float dsum[64];
    int b = blockIdx.x;
    int gi = 0;
    while (gi < tab.ng - 1 && b >= tab.g[gi].nrb) { b -= tab.g[gi].nrb; ++gi; }
    const GG G = tab.g[gi];

    const int tid = threadIdx.x;
    const int wid = tid >> 6;
    const int lane = tid & 63;
    const int l15 = lane & 15;
    const int quad = lane >> 4;
    const int g = wid >> 1;       // m-half
    const int h = wid & 1;        // n-half
    const int K = G.K;
    const int nch = K >> 5;
    const size_t row0 = (size_t)b * 64 + g * 32 + l15;
    // W frag base: lane's row (h*80 + nt*16 + l15), k-offset quad*8 within chunk
    const unsigned short* Wbase = G.W + ((h * 80 + l15) << 5) + (quad << 3);

    f32x4 acc[2][5];
    #pragma unroll
    for (int mt = 0; mt < 2; ++mt)
        #pragma unroll
        for (int nt = 0; nt < 5; ++nt) acc[mt][nt] = (f32x4){0.f, 0.f, 0.f, 0.f};

    short8 avc[2], bvc[5], bvn[5];
    f32x4 fr[2][2];

    // prologue: chunk 0
    #pragma unroll
    for (int nt = 0; nt < 5; ++nt) bvc[nt] = *(const short8*)(Wbase + nt * 512);
    if (G.a_fp32) {
        const float* A = (const float*)G.A;
        #pragma unroll
        for (int mt = 0; mt < 2; ++mt) {
            const float* p = A + (row0 + mt * 16) * G.lda + quad * 8;
            fr[mt][0] = *(const f32x4*)p;
            fr[mt][1] = *(const f32x4*)(p + 4);
        }
        avc[0] = cast8(fr[0][0], fr[0][1]);
        avc[1] = cast8(fr[1][0], fr[1][1]);
    } else {
        const unsigned short* A = (const unsigned short*)G.A;
        avc[0] = *(const short8*)(A + row0 * G.lda + quad * 8);
        avc[1] = *(const short8*)(A + (row0 + 16) * G.lda + quad * 8);
    }

    for (int c = 0; c < nch; ++c) {
        const bool more = (c + 1 < nch);
        short8 avn0, avn1;
        if (more) {
            const unsigned short* Wc = Wbase + (size_t)(c + 1) * 5120;
            #pragma unroll
            for (int nt = 0; nt < 5; ++nt) bvn[nt] = *(const short8*)(Wc + nt * 512);
            const int kn = (c + 1) << 5;
            if (G.a_fp32) {
                const float* A = (const float*)G.A;
                #pragma unroll
                for (int mt = 0; mt < 2; ++mt) {
                    const float* p = A + (row0 + mt * 16) * G.lda + kn + quad * 8;
                    fr[mt][0] = *(const f32x4*)p;
                    fr[mt][1] = *(const f32x4*)(p + 4);
                }
            } else {
                const unsigned short* A = (const unsigned short*)G.A;
                avn0 = *(const short8*)(A + row0 * G.lda + kn + quad * 8);
                avn1 = *(const short8*)(A + (row0 + 16) * G.lda + kn + quad * 8);
            }
        }
        #pragma unroll
        for (int nt = 0; nt < 5; ++nt) {
            acc[0][nt] = __builtin_amdgcn_mfma_f32_16x16x32_bf16(avc[0], bvc[nt], acc[0][nt], 0, 0, 0);
            acc[1][nt] = __builtin_amdgcn_mfma_f32_16x16x32_bf16(avc[1], bvc[nt], acc[1][nt], 0, 0, 0);
        }
        if (more) {
            #pragma unroll
            for (int nt = 0; nt < 5; ++nt) bvc[nt] = bvn[nt];
            if (G.a_fp32) {
                avc[0] = cast8(fr[0][0], fr[0][1]);
                avc[1] = cast8(fr[1][0], fr[1][1]);
            } else {
                avc[0] = avn0; avc[1] = avn1;
            }
        }
    }

    if (G.dotout) {
        // h2 = relu(acc+bias); partial dot over this wave's 5 nt; cross-wave
        // (h=0 vs h=1) combine via LDS; single barrier.
        float pp[2][4];
        #pragma unroll
        for (int mt = 0; mt < 2; ++mt)
            #pragma unroll
            for (int r = 0; r < 4; ++r) pp[mt][r] = 0.f;
        #pragma unroll
        for (int nt = 0; nt < 5; ++nt) {
            int col = h * 80 + nt * 16 + l15;
            float bv_ = (col < HID) ? G.bias[col] : 0.f;
            float vv = (col < HID) ? G.dotv[col] : 0.f;
            #pragma unroll
            for (int mt = 0; mt < 2; ++mt)
                #pragma unroll
                for (int r = 0; r < 4; ++r)
                    pp[mt][r] += fmaxf(acc[mt][nt][r] + bv_, 0.f) * vv;
        }
        #pragma unroll
        for (int mt = 0; mt < 2; ++mt)
            #pragma unroll
            for (int r = 0; r < 4; ++r) {
                #pragma unroll
                for (int off = 1; off < 16; off <<= 1)
                    pp[mt][r] += __shfl_xor(pp[mt][r], off);
            }
        if (h == 0 && l15 == 0) {
            #pragma unroll
            for (int mt = 0; mt < 2; ++mt)
                #pragma unroll
                for (int r = 0; r < 4; ++r)
                    dsum[g * 32 + mt * 16 + quad * 4 + r] = pp[mt][r];
        }
        __syncthreads();
        if (h == 1 && l15 == 0) {
            #pragma unroll
            for (int mt = 0; mt < 2; ++mt)
                #pragma unroll
                for (int r = 0; r < 4; ++r) {
                    int lr = g * 32 + mt * 16 + quad * 4 + r;
                    G.dotout[(size_t)b * 64 + lr] = dsum[lr] + pp[mt][r] + G.dotb[0];
                }
        }
    } else {
        #pragma unroll
        for (int nt = 0; nt < 5; ++nt) {
            int col = h * 80 + nt * 16 + l15;
            float bv_ = (G.bias != nullptr && col < HID) ? G.bias[col] : 0.f;
            #pragma unroll
            for (int mt = 0; mt < 2; ++mt)
                #pragma unroll
                for (int r = 0; r < 4; ++r) {
                    size_t row = (size_t)b * 64 + g * 32 + mt * 16 + quad * 4 + r;
                    float v = acc[mt][nt][r] + bv_;
                    if (G.relu) v = fmaxf(v, 0.f);
                    G.outh[row * G.ldo + col] = f2bf(v);
                }
        }
    }
}

// ---------------------------------------------------------------------------
// span layer-1: one wave per span; bf16 P gathers via u32 pairs.
// ---------------------------------------------------------------------------
__global__ __launch_bounds__(256) void span_l1_kernel(const float* __restrict__ attns,
                                                      const int* __restrict__ starts,
                                                      const int* __restrict__ lens,
                                                      const unsigned short* __restrict__ Ps,
                                                      const unsigned short* __restrict__ Pe,
                                                      const unsigned short* __restrict__ Pm,
                                                      const float* __restrict__ PW,
                                                      const float* __restrict__ bs1,
                                                      unsigned short* __restrict__ SH1) {
    const int wid = threadIdx.x >> 6, lane = threadIdx.x & 63;
    const int s = blockIdx.x * 4 + wid;
    const int start = starts[s];
    const int len = lens[s];

    const int iv = min(start + lane, T_TOK - 1);
    float a = (lane <= len) ? attns[iv] : -INFINITY;
    float m = a;
    #pragma unroll
    for (int off = 32; off; off >>= 1) m = fmaxf(m, __shfl_xor(m, off));
    float e = (lane <= len) ? __expf(a - m) : 0.f;
    float ssum = e;
    #pragma unroll
    for (int off = 32; off; off >>= 1) ssum += __shfl_xor(ssum, off);
    float wv = e / ssum;

    float wl[10]; int il[10];
    #pragma unroll
    for (int l = 0; l < 10; ++l) { wl[l] = __shfl(wv, l); il[l] = __shfl(iv, l); }

    const int end = start + len;
    const int width = len + 1;
    const int bucket = (width >= 1) + (width >= 2) + (width >= 3) + (width >= 4) +
                       (width >= 8) + (width >= 16) + (width >= 32) + (width >= 64);

    const unsigned short* ps = Ps + (size_t)start * 160;
    const unsigned short* pe = Pe + (size_t)end * 160;
    const float* pw = PW + bucket * HID;

    for (int p = lane; p < 75; p += 64) {
        const int j = 2 * p;
        unsigned int u0 = *(const unsigned int*)(ps + j);
        unsigned int u1 = *(const unsigned int*)(pe + j);
        float a0 = bs1[j]     + bf2f(u0 & 0xffff) + bf2f(u1 & 0xffff) + pw[j];
        float a1 = bs1[j + 1] + bf2f(u0 >> 16)    + bf2f(u1 >> 16)    + pw[j + 1];
        #pragma unroll
        for (int l = 0; l < 10; ++l) {
            unsigned int um = *(const unsigned int*)(Pm + (size_t)il[l] * 160 + j);
            a0 = fmaf(wl[l], bf2f(um & 0xffff), a0);
            a1 = fmaf(wl[l], bf2f(um >> 16), a1);
        }
        unsigned int packed = (unsigned int)f2bf(fmaxf(a0, 0.f)) |
                              ((unsigned int)f2bf(fmaxf(a1, 0.f)) << 16);
        *(unsigned int*)(SH1 + (size_t)s * 192 + j) = packed;
    }
}

extern "C" void kernel_launch(void* const* d_in, const int* in_sizes, int n_in,
                              void* d_out, int out_size, void* d_ws, size_t ws_size,
                              hipStream_t stream) {
    const float* states = (const float*)d_in[0];
    const float* embeds = (const float*)d_in[1];
    const int* span_starts = (const int*)d_in[2];
    const int* span_lengths = (const int*)d_in[3];
    const float* Wa1 = (const float*)d_in[4];
    const float* ba1 = (const float*)d_in[5];
    const float* Wa2 = (const float*)d_in[6];
    const float* ba2 = (const float*)d_in[7];
    const float* Wa3 = (const float*)d_in[8];
    const float* ba3 = (const float*)d_in[9];
    const float* width_table = (const float*)d_in[10];
    const float* Ws1 = (const float*)d_in[11];
    const float* bs1 = (const float*)d_in[12];
    const float* Ws2 = (const float*)d_in[13];
    const float* bs2 = (const float*)d_in[14];
    const float* Ws3 = (const float*)d_in[15];
    const float* bs3 = (const float*)d_in[16];
    float* out = (float*)d_out;

    // ---- workspace layout ----
    char* w = (char*)d_ws;
    unsigned short* WtA  = (unsigned short*)w;  w += 480 * 1024 * 2;
    unsigned short* WtE  = (unsigned short*)w;  w += 160 * 512 * 2;
    unsigned short* Wa2t = (unsigned short*)w;  w += 160 * 192 * 2;
    unsigned short* Ws2t = (unsigned short*)w;  w += 160 * 192 * 2;
    float* PW    = (float*)w;                   w += 5632;
    float* attns = (float*)w;                   w += 8192 * 4;
    unsigned short* Psh = (unsigned short*)w;   w += (size_t)T_TOK * 160 * 2;   // bf16
    unsigned short* Peh = (unsigned short*)w;   w += (size_t)T_TOK * 160 * 2;   // bf16
    unsigned short* Pmh = (unsigned short*)w;   w += (size_t)T_TOK * 160 * 2;   // bf16
    unsigned short* H1A = (unsigned short*)w;   w += (size_t)T_TOK * 192 * 2;   // bf16
    unsigned short* SH1 = (unsigned short*)w;   w += (size_t)S_SPAN * 192 * 2;  // bf16
    // No memsets: pad cols (0xAA poison = finite bf16) multiply zeroed W rows.

    // ---- prep: blocked weight transposes + width proj ----
    PrepTab pt;
    pt.g[0] = { Wa1,              WtA,              1024, 1024, 16 };
    pt.g[1] = { Ws1,              WtA + 160*1024,   1024, 1024, 16 };
    pt.g[2] = { Ws1 + 1024*150,   WtA + 320*1024,   1024, 1024, 16 };
    pt.g[3] = { Ws1 + 2048*150,   WtE,               512,  512,  8 };
    pt.g[4] = { Wa2,              Wa2t,              150,  192,  3 };
    pt.g[5] = { Ws2,              Ws2t,              150,  192,  3 };
    pt.wt = width_table; pt.Ws1w = Ws1 + 2560*150; pt.PW = PW;
    prep_kernel<<<62 + 9, 256, 0, stream>>>(pt);

    GG z = {};

    // ---- fused GEMM1+2: 4 groups (fp32 A, in-reg cast), 512 blocks ----
    GTab t1; t1.ng = 4;
    t1.g[0] = z; t1.g[0].A = states; t1.g[0].lda = 1024; t1.g[0].a_fp32 = 1;
    t1.g[0].W = WtA;            t1.g[0].K = 1024; t1.g[0].nrb = 128;
    t1.g[0].outh = H1A; t1.g[0].ldo = 192; t1.g[0].bias = ba1; t1.g[0].relu = 1;
    t1.g[1] = z; t1.g[1].A = states; t1.g[1].lda = 1024; t1.g[1].a_fp32 = 1;
    t1.g[1].W = WtA + 160*1024; t1.g[1].K = 1024; t1.g[1].nrb = 128;
    t1.g[1].outh = Psh; t1.g[1].ldo = 160;
    t1.g[2] = z; t1.g[2].A = states; t1.g[2].lda = 1024; t1.g[2].a_fp32 = 1;
    t1.g[2].W = WtA + 320*1024; t1.g[2].K = 1024; t1.g[2].nrb = 128;
    t1.g[2].outh = Peh; t1.g[2].ldo = 160;
    t1.g[3] = z; t1.g[3].A = embeds; t1.g[3].lda = 512;  t1.g[3].a_fp32 = 1;
    t1.g[3].W = WtE;            t1.g[3].K = 512;  t1.g[3].nrb = 128;
    t1.g[3].outh = Pmh; t1.g[3].ldo = 160;
    gemm_fused<<<512, 256, 0, stream>>>(t1);

    // ---- attn layer2 + fused layer3 dot -> attns ----
    GTab t2; t2.ng = 1;
    t2.g[0] = z; t2.g[0].A = H1A; t2.g[0].lda = 192; t2.g[0].a_fp32 = 0;
    t2.g[0].W = Wa2t; t2.g[0].K = 192; t2.g[0].nrb = 128;
    t2.g[0].bias = ba2; t2.g[0].dotv = Wa3; t2.g[0].dotb = ba3; t2.g[0].dotout = attns;
    gemm_fused<<<128, 256, 0, stream>>>(t2);

    // ---- span layer1 -> SH1 (bf16) ----
    span_l1_kernel<<<S_SPAN / 4, 256, 0, stream>>>(attns, span_starts, span_lengths,
                                                   Psh, Peh, Pmh, PW, bs1, SH1);

    // ---- span layer2 + fused layer3 dot -> out ----
    GTab t3; t3.ng = 1;
    t3.g[0] = z; t3.g[0].A = SH1; t3.g[0].lda = 192; t3.g[0].a_fp32 = 0;
    t3.g[0].W = Ws2t; t3.g[0].K = 192; t3.g[0].nrb = 512;
    t3.g[0].bias = bs2; t3.g[0].dotv = Ws3; t3.g[0].dotb = bs3; t3.g[0].dotout = out;
    gemm_fused<<<512, 256, 0, stream>>>(t3);
}

// Round 9
// 179.577 us; speedup vs baseline: 1.1578x; 1.1578x over previous
//
#include <hip/hip_runtime.h>
#include <math.h>

#define T_TOK 8192
#define A_DIM 1024
#define E_DIM 512
#define S_SPAN 32768
#define HID 150

typedef __attribute__((ext_vector_type(8))) short short8;
typedef __attribute__((ext_vector_type(4))) float f32x4;
typedef __attribute__((ext_vector_type(4))) unsigned int u32x4;
typedef __attribute__((ext_vector_type(4))) unsigned short u16x4;

__device__ __forceinline__ unsigned short f2bf(float f) {
    unsigned int u = __builtin_bit_cast(unsigned int, f);
    u += 0x7FFFu + ((u >> 16) & 1u);          // RNE
    return (unsigned short)(u >> 16);
}

// ---------------------------------------------------------------------------
// fused prep: input cast (fp32->bf16) + 6 weight transposes + width proj
// ---------------------------------------------------------------------------
#define NS4 (T_TOK * A_DIM / 4)   // 2097152
#define NE4 (T_TOK * E_DIM / 4)   // 1048576
#define NCAST ((NS4 + NE4) / 256) // 12288 exactly

struct WConv { const float* src; unsigned short* dst; int K0; int Kpad; int nblk; };
struct PrepTab {
    const float* s; const float* e; unsigned short* sd; unsigned short* ed;
    WConv g[6];
    const float* wt; const float* Ws1w; float* PW;
};

__global__ __launch_bounds__(256) void prep_kernel(PrepTab tab) {
    int b = blockIdx.x;
    if (b < NCAST) {
        int idx = b * 256 + threadIdx.x;
        const float* src; unsigned short* dst;
        if (idx < NS4) { src = tab.s; dst = tab.sd; }
        else { idx -= NS4; src = tab.e; dst = tab.ed; }
        f32x4 v = *(const f32x4*)(src + (size_t)idx * 4);
        u16x4 o;
        o.x = f2bf(v.x); o.y = f2bf(v.y); o.z = f2bf(v.z); o.w = f2bf(v.w);
        *(u16x4*)(dst + (size_t)idx * 4) = o;
        return;
    }
    b -= NCAST;
    #pragma unroll
    for (int gi = 0; gi < 6; ++gi) {
        if (b < tab.g[gi].nblk) {
            int idx = b * 256 + threadIdx.x;               // idx = k*160 + j
            int Kpad = tab.g[gi].Kpad;
            if (idx < Kpad * 160) {
                int k = idx / 160, j = idx - k * 160;
                float v = (j < HID && k < tab.g[gi].K0)
                          ? tab.g[gi].src[(size_t)k * HID + j] : 0.f;   // coalesced read
                tab.g[gi].dst[(size_t)j * Kpad + k] = f2bf(v);          // scattered write
            }
            return;
        }
        b -= tab.g[gi].nblk;
    }
    // width projection: 9 blocks
    int j = threadIdx.x;
    if (j < HID) {
        float acc = 0.f;
        for (int k = 0; k < 20; ++k)
            acc = fmaf(tab.wt[b * 20 + k], tab.Ws1w[k * HID + j], acc);
        tab.PW[b * HID + j] = acc;
    }
}

// ---------------------------------------------------------------------------
// unified MFMA GEMM, double-buffered + software-pipelined (R4 structure).
// per group: C[M x 160] = A(bf16,[M x K]) @ W(bf16,[160 x K] k-contig)
// block = 4 waves x 16 rows = 64 rows, 10 n-tiles, BK=64, 2 LDS buffers.
// LDW=72: 160*72*2*2 = 46.1 KB -> 3 blocks/CU (vs 2 at LDW=88).
// 144 B rows are 16B-aligned; 2-way bank alias only (free).
// epilogue: fp32 store / bf16 store (+bias+relu) or fused final dot.
// ---------------------------------------------------------------------------
struct GG {
    const unsigned short* A; int lda;
    const unsigned short* W; int K; int nrb;
    float* outf; unsigned short* outh; int ldo;
    const float* bias; int relu;
    const float* dotv; const float* dotb; float* dotout;
};
struct GTab { GG g[4]; int ng; };

template <int TAG>
__global__ __launch_bounds__(256) void gemm_fused(GTab tab) {
    constexpr int LDW = 72;
    __shared__ unsigned short WtL[2][160 * LDW];

    int b = blockIdx.x;
    int gi = 0;
    while (gi < tab.ng - 1 && b >= tab.g[gi].nrb) { b -= tab.g[gi].nrb; ++gi; }
    const GG G = tab.g[gi];

    const int tid = threadIdx.x;
    const int wid = tid >> 6;
    const int lane = tid & 63;
    const int l15 = lane & 15;
    const int quad = lane >> 4;
    const int row0 = b * 64 + wid * 16 + l15;
    const int K = G.K;
    const int nch = K >> 6;
    const unsigned short* Arow = G.A + (size_t)row0 * G.lda;

    // staging registers for W chunk: 1280 16B units / 256 thr = 5 each
    u32x4 stg[5];
    int sn[5], sk[5];
    #pragma unroll
    for (int i = 0; i < 5; ++i) { int u = tid + i * 256; sn[i] = u >> 3; sk[i] = (u & 7) * 8; }

    f32x4 acc[10];
    #pragma unroll
    for (int nt = 0; nt < 10; ++nt) acc[nt] = (f32x4){0.f, 0.f, 0.f, 0.f};

    #pragma unroll
    for (int i = 0; i < 5; ++i)
        stg[i] = *(const u32x4*)(G.W + (size_t)sn[i] * K + sk[i]);
    short8 avc0 = *(const short8*)(Arow + quad * 8);
    short8 avc1 = *(const short8*)(Arow + 32 + quad * 8);
    #pragma unroll
    for (int i = 0; i < 5; ++i)
        *(u32x4*)&WtL[0][sn[i] * LDW + sk[i]] = stg[i];
    __syncthreads();

    for (int c = 0; c < nch; ++c) {
        const int pb = c & 1;
        short8 avn0, avn1;
        const bool more = (c + 1 < nch);
        if (more) {
            const int kn = (c + 1) << 6;
            #pragma unroll
            for (int i = 0; i < 5; ++i)
                stg[i] = *(const u32x4*)(G.W + (size_t)sn[i] * K + kn + sk[i]);
            avn0 = *(const short8*)(Arow + kn + quad * 8);
            avn1 = *(const short8*)(Arow + kn + 32 + quad * 8);
        }
        #pragma unroll
        for (int nt = 0; nt < 10; ++nt) {
            short8 bv0 = *(const short8*)&WtL[pb][(nt * 16 + l15) * LDW + quad * 8];
            acc[nt] = __builtin_amdgcn_mfma_f32_16x16x32_bf16(avc0, bv0, acc[nt], 0, 0, 0);
            short8 bv1 = *(const short8*)&WtL[pb][(nt * 16 + l15) * LDW + 32 + quad * 8];
            acc[nt] = __builtin_amdgcn_mfma_f32_16x16x32_bf16(avc1, bv1, acc[nt], 0, 0, 0);
        }
        if (more) {
            #pragma unroll
            for (int i = 0; i < 5; ++i)
                *(u32x4*)&WtL[pb ^ 1][sn[i] * LDW + sk[i]] = stg[i];
            avc0 = avn0; avc1 = avn1;
        }
        __syncthreads();
    }

    const int rbase = b * 64 + wid * 16 + quad * 4;
    if (G.dotout) {
        float part[4] = {0.f, 0.f, 0.f, 0.f};
        #pragma unroll
        for (int nt = 0; nt < 10; ++nt) {
            int col = nt * 16 + l15;
            float bv_ = (col < HID) ? G.bias[col] : 0.f;
            float vv = (col < HID) ? G.dotv[col] : 0.f;
            #pragma unroll
            for (int r = 0; r < 4; ++r)
                part[r] += fmaxf(acc[nt][r] + bv_, 0.f) * vv;
        }
        #pragma unroll
        for (int r = 0; r < 4; ++r) {
            float p = part[r];
            #pragma unroll
            for (int off = 1; off < 16; off <<= 1) p += __shfl_xor(p, off);
            if (l15 == 0) G.dotout[rbase + r] = p + G.dotb[0];
        }
    } else {
        #pragma unroll
        for (int nt = 0; nt < 10; ++nt) {
            int col = nt * 16 + l15;
            float bv_ = (G.bias != nullptr && col < HID) ? G.bias[col] : 0.f;
            #pragma unroll
            for (int r = 0; r < 4; ++r) {
                int row = rbase + r;
                float v = acc[nt][r] + bv_;
                if (G.relu) v = fmaxf(v, 0.f);
                if (G.outh) G.outh[(size_t)row * G.ldo + col] = f2bf(v);
                else        G.outf[(size_t)row * G.ldo + col] = v;
            }
        }
    }
}

// ---------------------------------------------------------------------------
// span layer-1: one wave per span; fp32 P reads; writes SH1 bf16 cols 0..149.
// ---------------------------------------------------------------------------
__global__ __launch_bounds__(256) void span_l1_kernel(const float* __restrict__ attns,
                                                      const int* __restrict__ starts,
                                                      const int* __restrict__ lens,
                                                      const float* __restrict__ Ps,
                                                      const float* __restrict__ Pe,
                                                      const float* __restrict__ Pm,
                                                      const float* __restrict__ PW,
                                                      const float* __restrict__ bs1,
                                                      unsigned short* __restrict__ SH1) {
    const int wid = threadIdx.x >> 6, lane = threadIdx.x & 63;
    const int s = blockIdx.x * 4 + wid;
    const int start = starts[s];
    const int len = lens[s];

    const int iv = min(start + lane, T_TOK - 1);
    float a = (lane <= len) ? attns[iv] : -INFINITY;
    float m = a;
    #pragma unroll
    for (int off = 32; off; off >>= 1) m = fmaxf(m, __shfl_xor(m, off));
    float e = (lane <= len) ? __expf(a - m) : 0.f;
    float ssum = e;
    #pragma unroll
    for (int off = 32; off; off >>= 1) ssum += __shfl_xor(ssum, off);
    float wv = e / ssum;

    float wl[10]; int il[10];
    #pragma unroll
    for (int l = 0; l < 10; ++l) { wl[l] = __shfl(wv, l); il[l] = __shfl(iv, l); }

    const int end = start + len;
    const int width = len + 1;
    const int bucket = (width >= 1) + (width >= 2) + (width >= 3) + (width >= 4) +
                       (width >= 8) + (width >= 16) + (width >= 32) + (width >= 64);

    for (int j = lane; j < HID; j += 64) {
        float acc = bs1[j] + Ps[(size_t)start * 160 + j] + Pe[(size_t)end * 160 + j] +
                    PW[bucket * HID + j];
        #pragma unroll
        for (int l = 0; l < 10; ++l) acc = fmaf(wl[l], Pm[(size_t)il[l] * 160 + j], acc);
        SH1[(size_t)s * 192 + j] = f2bf(fmaxf(acc, 0.f));
    }
}

extern "C" void kernel_launch(void* const* d_in, const int* in_sizes, int n_in,
                              void* d_out, int out_size, void* d_ws, size_t ws_size,
                              hipStream_t stream) {
    const float* states = (const float*)d_in[0];
    const float* embeds = (const float*)d_in[1];
    const int* span_starts = (const int*)d_in[2];
    const int* span_lengths = (const int*)d_in[3];
    const float* Wa1 = (const float*)d_in[4];
    const float* ba1 = (const float*)d_in[5];
    const float* Wa2 = (const float*)d_in[6];
    const float* ba2 = (const float*)d_in[7];
    const float* Wa3 = (const float*)d_in[8];
    const float* ba3 = (const float*)d_in[9];
    const float* width_table = (const float*)d_in[10];
    const float* Ws1 = (const float*)d_in[11];
    const float* bs1 = (const float*)d_in[12];
    const float* Ws2 = (const float*)d_in[13];
    const float* bs2 = (const float*)d_in[14];
    const float* Ws3 = (const float*)d_in[15];
    const float* bs3 = (const float*)d_in[16];
    float* out = (float*)d_out;

    // ---- workspace layout ----
    char* w = (char*)d_ws;
    unsigned short* WtA  = (unsigned short*)w;  w += 480 * 1024 * 2;
    unsigned short* WtE  = (unsigned short*)w;  w += 160 * 512 * 2;
    unsigned short* Wa2t = (unsigned short*)w;  w += 160 * 192 * 2;
    unsigned short* Ws2t = (unsigned short*)w;  w += 160 * 192 * 2;
    float* PW    = (float*)w;                   w += 5632;
    float* attns = (float*)w;                   w += 8192 * 4;
    unsigned short* Sbf = (unsigned short*)w;   w += (size_t)T_TOK * A_DIM * 2;
    unsigned short* Ebf = (unsigned short*)w;   w += (size_t)T_TOK * E_DIM * 2;
    float* Ps = (float*)w;                      w += (size_t)T_TOK * 160 * 4;
    float* Pe = (float*)w;                      w += (size_t)T_TOK * 160 * 4;
    float* Pm = (float*)w;                      w += (size_t)T_TOK * 160 * 4;
    unsigned short* H1A = (unsigned short*)w;   w += (size_t)T_TOK * 192 * 2;   // bf16
    unsigned short* SH1 = (unsigned short*)w;   w += (size_t)S_SPAN * 192 * 2;  // bf16
    // No memsets: pad cols (0xAA poison = finite bf16) multiply zeroed W rows.

    // ---- fused prep: cast + weight transposes + width proj ----
    PrepTab pt;
    pt.s = states; pt.e = embeds; pt.sd = Sbf; pt.ed = Ebf;
    pt.g[0] = { Wa1,              WtA,              1024, 1024, (160*1024 + 255)/256 };
    pt.g[1] = { Ws1,              WtA + 160*1024,   1024, 1024, (160*1024 + 255)/256 };
    pt.g[2] = { Ws1 + 1024*150,   WtA + 320*1024,   1024, 1024, (160*1024 + 255)/256 };
    pt.g[3] = { Ws1 + 2048*150,   WtE,               512,  512, (160*512  + 255)/256 };
    pt.g[4] = { Wa2,              Wa2t,              150,  192, (160*192  + 255)/256 };
    pt.g[5] = { Ws2,              Ws2t,              150,  192, (160*192  + 255)/256 };
    pt.wt = width_table; pt.Ws1w = Ws1 + 2560*150; pt.PW = PW;
    int wblk = 0; for (int i = 0; i < 6; ++i) wblk += pt.g[i].nblk;
    prep_kernel<<<NCAST + wblk + 9, 256, 0, stream>>>(pt);

    GG z = {};

    // ---- fused GEMM1+2: 4 groups, 512 blocks (3 blocks/CU LDS-capped) ----
    GTab t1; t1.ng = 4;
    t1.g[0] = z; t1.g[0].A = Sbf; t1.g[0].lda = 1024; t1.g[0].W = WtA;            t1.g[0].K = 1024;
    t1.g[0].nrb = 128; t1.g[0].outh = H1A; t1.g[0].ldo = 192; t1.g[0].bias = ba1; t1.g[0].relu = 1;
    t1.g[1] = z; t1.g[1].A = Sbf; t1.g[1].lda = 1024; t1.g[1].W = WtA + 160*1024; t1.g[1].K = 1024;
    t1.g[1].nrb = 128; t1.g[1].outf = Ps;  t1.g[1].ldo = 160;
    t1.g[2] = z; t1.g[2].A = Sbf; t1.g[2].lda = 1024; t1.g[2].W = WtA + 320*1024; t1.g[2].K = 1024;
    t1.g[2].nrb = 128; t1.g[2].outf = Pe;  t1.g[2].ldo = 160;
    t1.g[3] = z; t1.g[3].A = Ebf; t1.g[3].lda = 512;  t1.g[3].W = WtE;            t1.g[3].K = 512;
    t1.g[3].nrb = 128; t1.g[3].outf = Pm;  t1.g[3].ldo = 160;
    gemm_fused<1><<<512, 256, 0, stream>>>(t1);

    // ---- attn layer2 + fused layer3 dot -> attns ----
    GTab t2; t2.ng = 1;
    t2.g[0] = z; t2.g[0].A = H1A; t2.g[0].lda = 192; t2.g[0].W = Wa2t; t2.g[0].K = 192;
    t2.g[0].nrb = 128; t2.g[0].bias = ba2; t2.g[0].dotv = Wa3; t2.g[0].dotb = ba3; t2.g[0].dotout = attns;
    gemm_fused<2><<<128, 256, 0, stream>>>(t2);

    // ---- span layer1 -> SH1 (bf16) ----
    span_l1_kernel<<<S_SPAN / 4, 256, 0, stream>>>(attns, span_starts, span_lengths,
                                                   Ps, Pe, Pm, PW, bs1, SH1);

    // ---- span layer2 + fused layer3 dot -> out ----
    GTab t3; t3.ng = 1;
    t3.g[0] = z; t3.g[0].A = SH1; t3.g[0].lda = 192; t3.g[0].W = Ws2t; t3.g[0].K = 192;
    t3.g[0].nrb = 512; t3.g[0].bias = bs2; t3.g[0].dotv = Ws3; t3.g[0].dotb = bs3; t3.g[0].dotout = out;
    gemm_fused<3><<<512, 256, 0, stream>>>(t3);
}